// Round 1
// baseline (435.910 us; speedup 1.0000x reference)
//
#include <hip/hip_runtime.h>

#define NEG_SLOPE 0.2f

// ---------------------------------------------------------------- CSR build

__global__ void count_k(const int* __restrict__ dst, int* __restrict__ cnt, int e) {
    int g = blockIdx.x * blockDim.x + threadIdx.x;
    if (g < e) atomicAdd(&cnt[dst[g]], 1);
}

__global__ void scan1(const int* __restrict__ cnt, int* __restrict__ offs,
                      int* __restrict__ partial, int n) {
    __shared__ int s[256];
    int tid = threadIdx.x;
    int g = blockIdx.x * 256 + tid;
    int v = (g < n) ? cnt[g] : 0;
    s[tid] = v;
    __syncthreads();
    for (int off = 1; off < 256; off <<= 1) {
        int t = (tid >= off) ? s[tid - off] : 0;
        __syncthreads();
        s[tid] += t;
        __syncthreads();
    }
    if (g < n) offs[g] = s[tid] - v;            // exclusive within block
    if (tid == 255) partial[blockIdx.x] = s[255];
}

__global__ void scan2(int* __restrict__ partial, int p) {
    __shared__ int s[256];
    int tid = threadIdx.x;
    int v = (tid < p) ? partial[tid] : 0;
    s[tid] = v;
    __syncthreads();
    for (int off = 1; off < 256; off <<= 1) {
        int t = (tid >= off) ? s[tid - off] : 0;
        __syncthreads();
        s[tid] += t;
        __syncthreads();
    }
    if (tid < p) partial[tid] = s[tid] - v;     // exclusive
}

__global__ void scan3(int* __restrict__ offs, const int* __restrict__ partial,
                      int n, int e) {
    int g = blockIdx.x * 256 + threadIdx.x;
    if (g < n) offs[g] += partial[blockIdx.x];
    if (g == 0) offs[n] = e;
}

__global__ void scatter_k(const int* __restrict__ src, const int* __restrict__ dst,
                          const int* __restrict__ offs, int* __restrict__ cursor,
                          int* __restrict__ csr_src, int e) {
    int g = blockIdx.x * blockDim.x + threadIdx.x;
    if (g < e) {
        int d = dst[g];
        int pos = atomicAdd(&cursor[d], 1);
        csr_src[offs[d] + pos] = src[g];
    }
}

// --------------------------------------------------- fused dual GEMM (fp32)
// C_l = A @ Wl + bl ; C_r = A @ Wr + br.  A:[N,128], W:[128,128].
// Block: 256 threads, 64 rows. Each thread: 4 rows x 8 cols x 2 matrices.

#define MB 64
#define KC 32

__global__ __launch_bounds__(256, 2) void gemm_dual(
    const float* __restrict__ A,
    const float* __restrict__ Wl, const float* __restrict__ bl,
    const float* __restrict__ Wr, const float* __restrict__ br,
    float* __restrict__ outl, float* __restrict__ outr)
{
    __shared__ float At[KC][MB + 4];     // transposed A chunk, 16B-aligned rows
    __shared__ float Wls[KC][128];
    __shared__ float Wrs[KC][128];

    const int tid = threadIdx.x;
    const int base = blockIdx.x * MB;
    const int r0 = (tid >> 4) << 2;      // 0..60
    const int c0 = (tid & 15) << 3;      // 0..120

    float accl[4][8], accr[4][8];
#pragma unroll
    for (int i = 0; i < 4; ++i)
#pragma unroll
        for (int j = 0; j < 8; ++j) { accl[i][j] = 0.f; accr[i][j] = 0.f; }

    for (int kc = 0; kc < 128; kc += KC) {
        // stage A chunk (64 rows x 32 k), transposed
#pragma unroll
        for (int it = 0; it < 2; ++it) {
            int f = tid + it * 256;
            int row = f >> 3, kq = (f & 7) << 2;
            const float4 v = *(const float4*)&A[(size_t)(base + row) * 128 + kc + kq];
            At[kq + 0][row] = v.x; At[kq + 1][row] = v.y;
            At[kq + 2][row] = v.z; At[kq + 3][row] = v.w;
        }
        // stage W chunks (32 k x 128 cols), row-major
#pragma unroll
        for (int it = 0; it < 4; ++it) {
            int f = tid + it * 256;
            int kk = f >> 5, cq = (f & 31) << 2;
            *(float4*)&Wls[kk][cq] = *(const float4*)&Wl[(size_t)(kc + kk) * 128 + cq];
            *(float4*)&Wrs[kk][cq] = *(const float4*)&Wr[(size_t)(kc + kk) * 128 + cq];
        }
        __syncthreads();

#pragma unroll
        for (int kk = 0; kk < KC; ++kk) {
            const float4 a  = *(const float4*)&At[kk][r0];
            const float4 l0 = *(const float4*)&Wls[kk][c0];
            const float4 l1 = *(const float4*)&Wls[kk][c0 + 4];
            const float4 q0 = *(const float4*)&Wrs[kk][c0];
            const float4 q1 = *(const float4*)&Wrs[kk][c0 + 4];
            const float av[4] = {a.x, a.y, a.z, a.w};
            const float wl[8] = {l0.x, l0.y, l0.z, l0.w, l1.x, l1.y, l1.z, l1.w};
            const float wr[8] = {q0.x, q0.y, q0.z, q0.w, q1.x, q1.y, q1.z, q1.w};
#pragma unroll
            for (int i = 0; i < 4; ++i)
#pragma unroll
                for (int j = 0; j < 8; ++j) {
                    accl[i][j] = fmaf(av[i], wl[j], accl[i][j]);
                    accr[i][j] = fmaf(av[i], wr[j], accr[i][j]);
                }
        }
        __syncthreads();
    }

    const float4 bl0 = *(const float4*)&bl[c0];
    const float4 bl1 = *(const float4*)&bl[c0 + 4];
    const float4 br0 = *(const float4*)&br[c0];
    const float4 br1 = *(const float4*)&br[c0 + 4];
#pragma unroll
    for (int i = 0; i < 4; ++i) {
        size_t row = (size_t)(base + r0 + i) * 128;
        float4 o;
        o.x = accl[i][0] + bl0.x; o.y = accl[i][1] + bl0.y;
        o.z = accl[i][2] + bl0.z; o.w = accl[i][3] + bl0.w;
        *(float4*)&outl[row + c0] = o;
        o.x = accl[i][4] + bl1.x; o.y = accl[i][5] + bl1.y;
        o.z = accl[i][6] + bl1.z; o.w = accl[i][7] + bl1.w;
        *(float4*)&outl[row + c0 + 4] = o;
        o.x = accr[i][0] + br0.x; o.y = accr[i][1] + br0.y;
        o.z = accr[i][2] + br0.z; o.w = accr[i][3] + br0.w;
        *(float4*)&outr[row + c0] = o;
        o.x = accr[i][4] + br1.x; o.y = accr[i][5] + br1.y;
        o.z = accr[i][6] + br1.z; o.w = accr[i][7] + br1.w;
        *(float4*)&outr[row + c0 + 4] = o;
    }
}

// -------------------------------------- per-node online-softmax aggregation
// One wave (64 lanes) per node; lane owns 2 of 128 feature dims.

__global__ __launch_bounds__(256) void attn_k(
    const float* __restrict__ xl, const float* __restrict__ xr,
    const int* __restrict__ offs, const int* __restrict__ csr_src,
    const float* __restrict__ att, const float* __restrict__ bias,
    float* __restrict__ out, int n)
{
    const int wid = (blockIdx.x * blockDim.x + threadIdx.x) >> 6;
    const int lane = threadIdx.x & 63;
    if (wid >= n) return;

    const int i0 = offs[wid];
    const int i1 = offs[wid + 1];
    const float2 xrv = *(const float2*)&xr[(size_t)wid * 128 + lane * 2];
    const float2 av  = *(const float2*)&att[lane * 2];

    float m = -INFINITY, l = 0.f, acc0 = 0.f, acc1 = 0.f;

    for (int i = i0; i < i1; ++i) {
        const int s = csr_src[i];
        const float2 xv = *(const float2*)&xl[(size_t)s * 128 + lane * 2];
        float t0 = xv.x + xrv.x; t0 = t0 > 0.f ? t0 : NEG_SLOPE * t0;
        float t1 = xv.y + xrv.y; t1 = t1 > 0.f ? t1 : NEG_SLOPE * t1;
        float part = t0 * av.x + t1 * av.y;
#pragma unroll
        for (int off = 32; off > 0; off >>= 1)
            part += __shfl_xor(part, off, 64);
        const float mn = fmaxf(m, part);
        const float sc = __expf(m - mn);     // exp(-inf)=0 on first edge
        const float p  = __expf(part - mn);
        l = l * sc + p;
        acc0 = acc0 * sc + p * xv.x;
        acc1 = acc1 * sc + p * xv.y;
        m = mn;
    }

    const float inv = 1.0f / fmaxf(l, 1e-16f);
    float o0 = acc0 * inv + bias[lane * 2];
    float o1 = acc1 * inv + bias[lane * 2 + 1];
    o0 = fmaxf(o0, 0.f);                     // ReLU after each layer
    o1 = fmaxf(o1, 0.f);
    *(float2*)&out[(size_t)wid * 128 + lane * 2] = make_float2(o0, o1);
}

// ---------------------------------------------------------------- launcher

extern "C" void kernel_launch(void* const* d_in, const int* in_sizes, int n_in,
                              void* d_out, int out_size, void* d_ws, size_t ws_size,
                              hipStream_t stream) {
    const float* x    = (const float*)d_in[0];
    const int*   ei   = (const int*)d_in[1];
    const float* Wl1  = (const float*)d_in[2];
    const float* bl1  = (const float*)d_in[3];
    const float* Wr1  = (const float*)d_in[4];
    const float* br1  = (const float*)d_in[5];
    const float* att1 = (const float*)d_in[6];
    const float* b1   = (const float*)d_in[7];
    const float* Wl2  = (const float*)d_in[8];
    const float* bl2  = (const float*)d_in[9];
    const float* Wr2  = (const float*)d_in[10];
    const float* br2  = (const float*)d_in[11];
    const float* att2 = (const float*)d_in[12];
    const float* b2   = (const float*)d_in[13];

    const int N = in_sizes[0] / 128;   // 40000
    const int E = in_sizes[1] / 2;     // 640000
    const int* srcp = ei;
    const int* dstp = ei + E;

    char* ws = (char*)d_ws;
    float* xl      = (float*)ws;  ws += (size_t)N * 128 * 4;
    float* xr      = (float*)ws;  ws += (size_t)N * 128 * 4;
    int*   csr_src = (int*)ws;    ws += (size_t)E * 4;
    int*   offs    = (int*)ws;    ws += ((size_t)N + 4) * 4;
    int*   cnt     = (int*)ws;    ws += (size_t)N * 4;
    int*   cursor  = (int*)ws;    ws += (size_t)N * 4;
    int*   partial = (int*)ws;
    float* h = (float*)d_out;          // layer-1 activations (rewritten by layer 2)

    const int scanBlocks = (N + 255) / 256;       // 157
    const int eBlocks = (E + 255) / 256;          // 2500

    // zero cnt + cursor (contiguous)
    hipMemsetAsync(cnt, 0, (size_t)N * 2 * 4, stream);

    // ---- CSR by dst (shared by both layers) ----
    count_k<<<eBlocks, 256, 0, stream>>>(dstp, cnt, E);
    scan1<<<scanBlocks, 256, 0, stream>>>(cnt, offs, partial, N);
    scan2<<<1, 256, 0, stream>>>(partial, scanBlocks);
    scan3<<<scanBlocks, 256, 0, stream>>>(offs, partial, N, E);
    scatter_k<<<eBlocks, 256, 0, stream>>>(srcp, dstp, offs, cursor, csr_src, E);

    const int gemmBlocks = N / MB;                // 625
    const int attnBlocks = (N + 3) / 4;           // 10000 (4 waves/block)

    // ---- layer 1 ----
    gemm_dual<<<gemmBlocks, 256, 0, stream>>>(x, Wl1, bl1, Wr1, br1, xl, xr);
    attn_k<<<attnBlocks, 256, 0, stream>>>(xl, xr, offs, csr_src, att1, b1, h, N);

    // ---- layer 2 ----
    gemm_dual<<<gemmBlocks, 256, 0, stream>>>(h, Wl2, bl2, Wr2, br2, xl, xr);
    attn_k<<<attnBlocks, 256, 0, stream>>>(xl, xr, offs, csr_src, att2, b2,
                                           (float*)d_out, N);
}

// Round 2
// 358.050 us; speedup vs baseline: 1.2175x; 1.2175x over previous
//
#include <hip/hip_runtime.h>

#define NEG_SLOPE 0.2f

// ---------------------------------------------------------------- CSR build

__global__ void count_k(const int* __restrict__ dst, int* __restrict__ cnt, int e) {
    int g = blockIdx.x * blockDim.x + threadIdx.x;
    if (g < e) atomicAdd(&cnt[dst[g]], 1);
}

__global__ void scan1(const int* __restrict__ cnt, int* __restrict__ offs,
                      int* __restrict__ partial, int n) {
    __shared__ int s[256];
    int tid = threadIdx.x;
    int g = blockIdx.x * 256 + tid;
    int v = (g < n) ? cnt[g] : 0;
    s[tid] = v;
    __syncthreads();
    for (int off = 1; off < 256; off <<= 1) {
        int t = (tid >= off) ? s[tid - off] : 0;
        __syncthreads();
        s[tid] += t;
        __syncthreads();
    }
    if (g < n) offs[g] = s[tid] - v;            // exclusive within block
    if (tid == 255) partial[blockIdx.x] = s[255];
}

__global__ void scan2(int* __restrict__ partial, int p) {
    __shared__ int s[256];
    int tid = threadIdx.x;
    int v = (tid < p) ? partial[tid] : 0;
    s[tid] = v;
    __syncthreads();
    for (int off = 1; off < 256; off <<= 1) {
        int t = (tid >= off) ? s[tid - off] : 0;
        __syncthreads();
        s[tid] += t;
        __syncthreads();
    }
    if (tid < p) partial[tid] = s[tid] - v;     // exclusive
}

__global__ void scan3(int* __restrict__ offs, const int* __restrict__ partial,
                      int n, int e) {
    int g = blockIdx.x * 256 + threadIdx.x;
    if (g < n) offs[g] += partial[blockIdx.x];
    if (g == 0) offs[n] = e;
}

__global__ void scatter_k(const int* __restrict__ src, const int* __restrict__ dst,
                          const int* __restrict__ offs, int* __restrict__ cursor,
                          int* __restrict__ csr_src, int e) {
    int g = blockIdx.x * blockDim.x + threadIdx.x;
    if (g < e) {
        int d = dst[g];
        int pos = atomicAdd(&cursor[d], 1);
        csr_src[offs[d] + pos] = src[g];
    }
}

// --------------------------------------------------- fused dual GEMM (fp32)
// C_l = A @ Wl + bl ; C_r = A @ Wr + br.  A:[N,128], W:[128,128].
// Block: 256 threads, 64 rows. Each thread: 4 rows x 8 cols x 2 matrices.

#define MB 64
#define KC 32

__global__ __launch_bounds__(256, 2) void gemm_dual(
    const float* __restrict__ A,
    const float* __restrict__ Wl, const float* __restrict__ bl,
    const float* __restrict__ Wr, const float* __restrict__ br,
    float* __restrict__ outl, float* __restrict__ outr)
{
    __shared__ float At[KC][MB + 4];     // transposed A chunk, 16B-aligned rows
    __shared__ float Wls[KC][128];
    __shared__ float Wrs[KC][128];

    const int tid = threadIdx.x;
    const int base = blockIdx.x * MB;
    const int r0 = (tid >> 4) << 2;      // 0..60
    const int c0 = (tid & 15) << 3;      // 0..120

    float accl[4][8], accr[4][8];
#pragma unroll
    for (int i = 0; i < 4; ++i)
#pragma unroll
        for (int j = 0; j < 8; ++j) { accl[i][j] = 0.f; accr[i][j] = 0.f; }

    for (int kc = 0; kc < 128; kc += KC) {
        // stage A chunk (64 rows x 32 k), transposed
#pragma unroll
        for (int it = 0; it < 2; ++it) {
            int f = tid + it * 256;
            int row = f >> 3, kq = (f & 7) << 2;
            const float4 v = *(const float4*)&A[(size_t)(base + row) * 128 + kc + kq];
            At[kq + 0][row] = v.x; At[kq + 1][row] = v.y;
            At[kq + 2][row] = v.z; At[kq + 3][row] = v.w;
        }
        // stage W chunks (32 k x 128 cols), row-major
#pragma unroll
        for (int it = 0; it < 4; ++it) {
            int f = tid + it * 256;
            int kk = f >> 5, cq = (f & 31) << 2;
            *(float4*)&Wls[kk][cq] = *(const float4*)&Wl[(size_t)(kc + kk) * 128 + cq];
            *(float4*)&Wrs[kk][cq] = *(const float4*)&Wr[(size_t)(kc + kk) * 128 + cq];
        }
        __syncthreads();

#pragma unroll
        for (int kk = 0; kk < KC; ++kk) {
            const float4 a  = *(const float4*)&At[kk][r0];
            const float4 l0 = *(const float4*)&Wls[kk][c0];
            const float4 l1 = *(const float4*)&Wls[kk][c0 + 4];
            const float4 q0 = *(const float4*)&Wrs[kk][c0];
            const float4 q1 = *(const float4*)&Wrs[kk][c0 + 4];
            const float av[4] = {a.x, a.y, a.z, a.w};
            const float wl[8] = {l0.x, l0.y, l0.z, l0.w, l1.x, l1.y, l1.z, l1.w};
            const float wr[8] = {q0.x, q0.y, q0.z, q0.w, q1.x, q1.y, q1.z, q1.w};
#pragma unroll
            for (int i = 0; i < 4; ++i)
#pragma unroll
                for (int j = 0; j < 8; ++j) {
                    accl[i][j] = fmaf(av[i], wl[j], accl[i][j]);
                    accr[i][j] = fmaf(av[i], wr[j], accr[i][j]);
                }
        }
        __syncthreads();
    }

    const float4 bl0 = *(const float4*)&bl[c0];
    const float4 bl1 = *(const float4*)&bl[c0 + 4];
    const float4 br0 = *(const float4*)&br[c0];
    const float4 br1 = *(const float4*)&br[c0 + 4];
#pragma unroll
    for (int i = 0; i < 4; ++i) {
        size_t row = (size_t)(base + r0 + i) * 128;
        float4 o;
        o.x = accl[i][0] + bl0.x; o.y = accl[i][1] + bl0.y;
        o.z = accl[i][2] + bl0.z; o.w = accl[i][3] + bl0.w;
        *(float4*)&outl[row + c0] = o;
        o.x = accl[i][4] + bl1.x; o.y = accl[i][5] + bl1.y;
        o.z = accl[i][6] + bl1.z; o.w = accl[i][7] + bl1.w;
        *(float4*)&outl[row + c0 + 4] = o;
        o.x = accr[i][0] + br0.x; o.y = accr[i][1] + br0.y;
        o.z = accr[i][2] + br0.z; o.w = accr[i][3] + br0.w;
        *(float4*)&outr[row + c0] = o;
        o.x = accr[i][4] + br1.x; o.y = accr[i][5] + br1.y;
        o.z = accr[i][6] + br1.z; o.w = accr[i][7] + br1.w;
        *(float4*)&outr[row + c0 + 4] = o;
    }
}

// -------------------------------------- per-node online-softmax aggregation
// One wave (64 lanes) per node; lane owns 2 of 128 feature dims.
// 4-edge unroll: 4 gathers + 4 shuffle-reduce chains in flight, merged into
// the online-softmax state once per group (associative rescale — exact).
// Edge indices cached one-per-lane per 64-edge chunk, fetched via __shfl.

__global__ __launch_bounds__(256) void attn_k(
    const float* __restrict__ xl, const float* __restrict__ xr,
    const int* __restrict__ offs, const int* __restrict__ csr_src,
    const float* __restrict__ att, const float* __restrict__ bias,
    float* __restrict__ out, int n)
{
    const int wid = (blockIdx.x * blockDim.x + threadIdx.x) >> 6;
    const int lane = threadIdx.x & 63;
    if (wid >= n) return;

    const int i0  = offs[wid];
    const int deg = offs[wid + 1] - i0;
    const float2 xrv = *(const float2*)&xr[(size_t)wid * 128 + lane * 2];
    const float2 av  = *(const float2*)&att[lane * 2];

    float m = -INFINITY, l = 0.f, acc0 = 0.f, acc1 = 0.f;

    for (int b = 0; b < deg; b += 64) {
        const int nb = min(64, deg - b);
        const int idx = (b + lane < deg) ? csr_src[i0 + b + lane] : 0;

        int e = 0;
        for (; e + 4 <= nb; e += 4) {
            const int s0 = __shfl(idx, e + 0);
            const int s1 = __shfl(idx, e + 1);
            const int s2 = __shfl(idx, e + 2);
            const int s3 = __shfl(idx, e + 3);
            const float2 x0 = *(const float2*)&xl[(size_t)s0 * 128 + lane * 2];
            const float2 x1 = *(const float2*)&xl[(size_t)s1 * 128 + lane * 2];
            const float2 x2 = *(const float2*)&xl[(size_t)s2 * 128 + lane * 2];
            const float2 x3 = *(const float2*)&xl[(size_t)s3 * 128 + lane * 2];

            float t;
            float p0, p1, p2, p3;
            t = x0.x + xrv.x; t = t > 0.f ? t : NEG_SLOPE * t; p0 = t * av.x;
            t = x0.y + xrv.y; t = t > 0.f ? t : NEG_SLOPE * t; p0 = fmaf(t, av.y, p0);
            t = x1.x + xrv.x; t = t > 0.f ? t : NEG_SLOPE * t; p1 = t * av.x;
            t = x1.y + xrv.y; t = t > 0.f ? t : NEG_SLOPE * t; p1 = fmaf(t, av.y, p1);
            t = x2.x + xrv.x; t = t > 0.f ? t : NEG_SLOPE * t; p2 = t * av.x;
            t = x2.y + xrv.y; t = t > 0.f ? t : NEG_SLOPE * t; p2 = fmaf(t, av.y, p2);
            t = x3.x + xrv.x; t = t > 0.f ? t : NEG_SLOPE * t; p3 = t * av.x;
            t = x3.y + xrv.y; t = t > 0.f ? t : NEG_SLOPE * t; p3 = fmaf(t, av.y, p3);

#pragma unroll
            for (int off = 32; off > 0; off >>= 1) {
                p0 += __shfl_xor(p0, off, 64);
                p1 += __shfl_xor(p1, off, 64);
                p2 += __shfl_xor(p2, off, 64);
                p3 += __shfl_xor(p3, off, 64);
            }

            const float mn = fmaxf(fmaxf(fmaxf(p0, p1), fmaxf(p2, p3)), m);
            const float sc = __expf(m - mn);     // exp(-inf)=0 on first group
            const float e0 = __expf(p0 - mn);
            const float e1 = __expf(p1 - mn);
            const float e2 = __expf(p2 - mn);
            const float e3 = __expf(p3 - mn);
            l = fmaf(l, sc, e0 + e1 + e2 + e3);
            acc0 = fmaf(acc0, sc,
                        fmaf(e0, x0.x, fmaf(e1, x1.x, fmaf(e2, x2.x, e3 * x3.x))));
            acc1 = fmaf(acc1, sc,
                        fmaf(e0, x0.y, fmaf(e1, x1.y, fmaf(e2, x2.y, e3 * x3.y))));
            m = mn;
        }

        for (; e < nb; ++e) {                     // tail (0-3 edges)
            const int s = __shfl(idx, e);
            const float2 xv = *(const float2*)&xl[(size_t)s * 128 + lane * 2];
            float t0 = xv.x + xrv.x; t0 = t0 > 0.f ? t0 : NEG_SLOPE * t0;
            float t1 = xv.y + xrv.y; t1 = t1 > 0.f ? t1 : NEG_SLOPE * t1;
            float part = fmaf(t1, av.y, t0 * av.x);
#pragma unroll
            for (int off = 32; off > 0; off >>= 1)
                part += __shfl_xor(part, off, 64);
            const float mn = fmaxf(m, part);
            const float sc = __expf(m - mn);
            const float p  = __expf(part - mn);
            l = fmaf(l, sc, p);
            acc0 = fmaf(acc0, sc, p * xv.x);
            acc1 = fmaf(acc1, sc, p * xv.y);
            m = mn;
        }
    }

    const float inv = 1.0f / fmaxf(l, 1e-16f);
    float o0 = fmaf(acc0, inv, bias[lane * 2]);
    float o1 = fmaf(acc1, inv, bias[lane * 2 + 1]);
    o0 = fmaxf(o0, 0.f);                     // ReLU after each layer
    o1 = fmaxf(o1, 0.f);
    *(float2*)&out[(size_t)wid * 128 + lane * 2] = make_float2(o0, o1);
}

// ---------------------------------------------------------------- launcher

extern "C" void kernel_launch(void* const* d_in, const int* in_sizes, int n_in,
                              void* d_out, int out_size, void* d_ws, size_t ws_size,
                              hipStream_t stream) {
    const float* x    = (const float*)d_in[0];
    const int*   ei   = (const int*)d_in[1];
    const float* Wl1  = (const float*)d_in[2];
    const float* bl1  = (const float*)d_in[3];
    const float* Wr1  = (const float*)d_in[4];
    const float* br1  = (const float*)d_in[5];
    const float* att1 = (const float*)d_in[6];
    const float* b1   = (const float*)d_in[7];
    const float* Wl2  = (const float*)d_in[8];
    const float* bl2  = (const float*)d_in[9];
    const float* Wr2  = (const float*)d_in[10];
    const float* br2  = (const float*)d_in[11];
    const float* att2 = (const float*)d_in[12];
    const float* b2   = (const float*)d_in[13];

    const int N = in_sizes[0] / 128;   // 40000
    const int E = in_sizes[1] / 2;     // 640000
    const int* srcp = ei;
    const int* dstp = ei + E;

    char* ws = (char*)d_ws;
    float* xl      = (float*)ws;  ws += (size_t)N * 128 * 4;
    float* xr      = (float*)ws;  ws += (size_t)N * 128 * 4;
    int*   csr_src = (int*)ws;    ws += (size_t)E * 4;
    int*   offs    = (int*)ws;    ws += ((size_t)N + 4) * 4;
    int*   cnt     = (int*)ws;    ws += (size_t)N * 4;
    int*   cursor  = (int*)ws;    ws += (size_t)N * 4;
    int*   partial = (int*)ws;
    float* h = (float*)d_out;          // layer-1 activations (rewritten by layer 2)

    const int scanBlocks = (N + 255) / 256;       // 157
    const int eBlocks = (E + 255) / 256;          // 2500

    // zero cnt + cursor (contiguous)
    hipMemsetAsync(cnt, 0, (size_t)N * 2 * 4, stream);

    // ---- CSR by dst (shared by both layers) ----
    count_k<<<eBlocks, 256, 0, stream>>>(dstp, cnt, E);
    scan1<<<scanBlocks, 256, 0, stream>>>(cnt, offs, partial, N);
    scan2<<<1, 256, 0, stream>>>(partial, scanBlocks);
    scan3<<<scanBlocks, 256, 0, stream>>>(offs, partial, N, E);
    scatter_k<<<eBlocks, 256, 0, stream>>>(srcp, dstp, offs, cursor, csr_src, E);

    const int gemmBlocks = N / MB;                // 625
    const int attnBlocks = (N + 3) / 4;           // 10000 (4 waves/block)

    // ---- layer 1 ----
    gemm_dual<<<gemmBlocks, 256, 0, stream>>>(x, Wl1, bl1, Wr1, br1, xl, xr);
    attn_k<<<attnBlocks, 256, 0, stream>>>(xl, xr, offs, csr_src, att1, b1, h, N);

    // ---- layer 2 ----
    gemm_dual<<<gemmBlocks, 256, 0, stream>>>(h, Wl2, bl2, Wr2, br2, xl, xr);
    attn_k<<<attnBlocks, 256, 0, stream>>>(xl, xr, offs, csr_src, att2, b2,
                                           (float*)d_out, N);
}